// Round 12
// baseline (555.929 us; speedup 1.0000x reference)
//
#include <hip/hip_runtime.h>
#include <hip/hip_bf16.h>
#include <stdint.h>

typedef __bf16 bf16x8 __attribute__((ext_vector_type(8)));
typedef __bf16 bf16x4 __attribute__((ext_vector_type(4)));
typedef float floatx4 __attribute__((ext_vector_type(4)));

typedef __attribute__((address_space(1))) void gvoid;
typedef __attribute__((address_space(3))) void lvoid;

__device__ __forceinline__ void async_load16(const __bf16* g, __bf16* l) {
  __builtin_amdgcn_global_load_lds((gvoid*)g, (lvoid*)l, 16, 0, 0);
}

__device__ __forceinline__ bf16x8 ld8(const float* p) {
  const floatx4 a = *(const floatx4*)p;
  const floatx4 b = *(const floatx4*)(p + 4);
  bf16x8 r;
  r[0] = (__bf16)a[0]; r[1] = (__bf16)a[1];
  r[2] = (__bf16)a[2]; r[3] = (__bf16)a[3];
  r[4] = (__bf16)b[0]; r[5] = (__bf16)b[1];
  r[6] = (__bf16)b[2]; r[7] = (__bf16)b[3];
  return r;
}

// fp32 -> bf16 elementwise (n multiple of 2048)
__global__ __launch_bounds__(256) void cvt_kernel(const float* __restrict__ in,
                                                  __bf16* __restrict__ out,
                                                  int n) {
  const int i = (blockIdx.x * 256 + threadIdx.x) * 8;
  if (i < n) *(bf16x8*)(out + i) = ld8(in + i);
}

// ---------------------------------------------------------------------------
// gemm8p: 256x256 BK=64 8-phase counted-vmcnt GEMM (m201-template port).
// 512 thr = 8 waves (2M x 4N); wave out 128x64 = acc[8][4]. Dynamic LDS
// 128 KiB: A/B x [2 buf][2 kh] planes of [256 x 32] bf16 (row 64B ->
// verified conflict-free frag reads). Per K-tile T (buf=T&1), 4 phases
// (mh,ks): {ds_read frags | stage 1 half-tile (2 gload_lds) | bar |
// lgkmcnt(0) | setprio(1) 16 MFMA setprio(0) | [vmcnt] | bar}.
// Stage stream: p0:A(T+1)kh1 p1:B(T+1)kh1 -> buf^1 (kh1 last read (T-1).p3,
// barrier-separated); p2:A(T+2)kh0 p3:B(T+2)kh0 -> buf (kh0 last read T.p1,
// barrier-separated). vmcnt ledger (2 loads/half, per wave):
//   end p1: retire (T)kh1 pair -> keep 4 halves -> vmcnt(8)   [NT-1: 0]
//   end p3: retire (T+1)kh0 pair -> keep 4 -> vmcnt(8)  [NT-2: 4, NT-1: 0]
// Never drains mid-loop (T4). Prologue: 6 halves, vmcnt(8), barrier.
// EPI: 0 QKV (q cols scaled 0.125, vT scatter), 2 relu(+bias).
// ---------------------------------------------------------------------------
#define MFMA16(AF, BFR, BASE)                                              \
  _Pragma("unroll") for (int mi = 0; mi < 4; ++mi)                         \
      _Pragma("unroll") for (int ni = 0; ni < 4; ++ni)                     \
          acc[(BASE) + mi][ni] = __builtin_amdgcn_mfma_f32_16x16x32_bf16(  \
              AF[mi], BFR[ni], acc[(BASE) + mi][ni], 0, 0, 0);

template <int EPI>
__global__ __launch_bounds__(512, 1) void gemm8p(
    const __bf16* __restrict__ A, const __bf16* __restrict__ Bt,
    const float* __restrict__ bias, const float* __restrict__ resf,
    const __bf16* __restrict__ resb, __bf16* __restrict__ o0,
    __bf16* __restrict__ o2, int M, int N, int K, int ldb) {
  extern __shared__ __bf16 smem[];  // 128 KiB: A planes [0,32768), B [32768,)
  const int tid = threadIdx.x;
  const int w = tid >> 6, lane = tid & 63;
  const int l16 = lane & 15, quad = lane >> 4;
  const int wm = w >> 2, wn = w & 3;
  const int bm = blockIdx.y * 256, bn = blockIdx.x * 256;
  const int NT = K >> 6;

  floatx4 acc[8][4];
#pragma unroll
  for (int i = 0; i < 8; ++i)
#pragma unroll
    for (int j = 0; j < 4; ++j) acc[i][j] = (floatx4){0.f, 0.f, 0.f, 0.f};

  // staging: thread -> row tid>>2 (0..127), col (tid&3)*8; inst2 = +128 rows
  const int strow = tid >> 2, stcol = (tid & 3) * 8;
  const __bf16* Ag = A + (int64_t)(bm + strow) * K + stcol;
  const __bf16* Bg = Bt + (int64_t)(bn + strow) * ldb + stcol;
  __bf16* AsB = smem;
  __bf16* BsB = smem + 32768;

  auto stageA = [&](int buf, int kh, int kofs) {
    __bf16* d = AsB + (buf * 2 + kh) * 8192 + w * 512;
    async_load16(Ag + kofs, d);
    async_load16(Ag + kofs + (int64_t)128 * K, d + 4096);
  };
  auto stageB = [&](int buf, int kh, int kofs) {
    __bf16* d = BsB + (buf * 2 + kh) * 8192 + w * 512;
    async_load16(Bg + kofs, d);
    async_load16(Bg + kofs + (int64_t)128 * ldb, d + 4096);
  };

  // prologue: A0kh0 B0kh0 A0kh1 B0kh1 A1kh0 B1kh0 (6 halves = 12 loads)
  stageA(0, 0, 0);  stageB(0, 0, 0);
  stageA(0, 1, 32); stageB(0, 1, 32);
  stageA(1, 0, 64); stageB(1, 0, 64);
  asm volatile("s_waitcnt vmcnt(8)" ::: "memory");  // tile0 kh0 landed
  __builtin_amdgcn_s_barrier();
  __builtin_amdgcn_sched_barrier(0);

  for (int T = 0; T < NT; ++T) {
    const int buf = T & 1;
    const __bf16* Ap0 = AsB + (buf * 2 + 0) * 8192;
    const __bf16* Ap1 = AsB + (buf * 2 + 1) * 8192;
    const __bf16* Bp0 = BsB + (buf * 2 + 0) * 8192;
    const __bf16* Bp1 = BsB + (buf * 2 + 1) * 8192;
    bf16x8 af[4], bfr[4];

    // ---- p0: mh0 ks0 ----
#pragma unroll
    for (int i = 0; i < 4; ++i)
      bfr[i] = *(const bf16x8*)(Bp0 + (wn * 64 + i * 16 + l16) * 32 + quad * 8);
#pragma unroll
    for (int i = 0; i < 4; ++i)
      af[i] = *(const bf16x8*)(Ap0 + (wm * 128 + i * 16 + l16) * 32 + quad * 8);
    if (T + 1 < NT) stageA(buf ^ 1, 1, (T + 1) * 64 + 32);
    __builtin_amdgcn_sched_barrier(0);
    __builtin_amdgcn_s_barrier();
    asm volatile("s_waitcnt lgkmcnt(0)" ::: "memory");
    __builtin_amdgcn_sched_barrier(0);
    __builtin_amdgcn_s_setprio(1);
    MFMA16(af, bfr, 0)
    __builtin_amdgcn_s_setprio(0);
    __builtin_amdgcn_sched_barrier(0);
    __builtin_amdgcn_s_barrier();

    // ---- p1: mh1 ks0 ----
#pragma unroll
    for (int i = 0; i < 4; ++i)
      af[i] = *(const bf16x8*)(Ap0 + (wm * 128 + 64 + i * 16 + l16) * 32 + quad * 8);
    if (T + 1 < NT) stageB(buf ^ 1, 1, (T + 1) * 64 + 32);
    __builtin_amdgcn_sched_barrier(0);
    __builtin_amdgcn_s_barrier();
    asm volatile("s_waitcnt lgkmcnt(0)" ::: "memory");
    __builtin_amdgcn_sched_barrier(0);
    __builtin_amdgcn_s_setprio(1);
    MFMA16(af, bfr, 4)
    __builtin_amdgcn_s_setprio(0);
    __builtin_amdgcn_sched_barrier(0);
    if (T == NT - 1) asm volatile("s_waitcnt vmcnt(0)" ::: "memory");
    else asm volatile("s_waitcnt vmcnt(8)" ::: "memory");  // (T)kh1 landed
    __builtin_amdgcn_sched_barrier(0);
    __builtin_amdgcn_s_barrier();

    // ---- p2: mh0 ks1 ----
#pragma unroll
    for (int i = 0; i < 4; ++i)
      bfr[i] = *(const bf16x8*)(Bp1 + (wn * 64 + i * 16 + l16) * 32 + quad * 8);
#pragma unroll
    for (int i = 0; i < 4; ++i)
      af[i] = *(const bf16x8*)(Ap1 + (wm * 128 + i * 16 + l16) * 32 + quad * 8);
    if (T + 2 < NT) stageA(buf, 0, (T + 2) * 64);
    __builtin_amdgcn_sched_barrier(0);
    __builtin_amdgcn_s_barrier();
    asm volatile("s_waitcnt lgkmcnt(0)" ::: "memory");
    __builtin_amdgcn_sched_barrier(0);
    __builtin_amdgcn_s_setprio(1);
    MFMA16(af, bfr, 0)
    __builtin_amdgcn_s_setprio(0);
    __builtin_amdgcn_sched_barrier(0);
    __builtin_amdgcn_s_barrier();

    // ---- p3: mh1 ks1 ----
#pragma unroll
    for (int i = 0; i < 4; ++i)
      af[i] = *(const bf16x8*)(Ap1 + (wm * 128 + 64 + i * 16 + l16) * 32 + quad * 8);
    if (T + 2 < NT) stageB(buf, 0, (T + 2) * 64);
    __builtin_amdgcn_sched_barrier(0);
    __builtin_amdgcn_s_barrier();
    asm volatile("s_waitcnt lgkmcnt(0)" ::: "memory");
    __builtin_amdgcn_sched_barrier(0);
    __builtin_amdgcn_s_setprio(1);
    MFMA16(af, bfr, 4)
    __builtin_amdgcn_s_setprio(0);
    __builtin_amdgcn_sched_barrier(0);
    if (T == NT - 2) asm volatile("s_waitcnt vmcnt(4)" ::: "memory");
    else if (T == NT - 1) asm volatile("s_waitcnt vmcnt(0)" ::: "memory");
    else asm volatile("s_waitcnt vmcnt(8)" ::: "memory");  // (T+1)kh0 landed
    __builtin_amdgcn_sched_barrier(0);
    __builtin_amdgcn_s_barrier();
  }

  // epilogue: C/D layout col = lane&15, row = quad*4 + reg  [m89-verified]
#pragma unroll
  for (int ni = 0; ni < 4; ++ni) {
    const int gn = bn + wn * 64 + ni * 16 + l16;
    const float bv = bias[gn];
#pragma unroll
    for (int ai = 0; ai < 8; ++ai) {
#pragma unroll
      for (int r = 0; r < 4; ++r) {
        const int gm = bm + wm * 128 + (ai >> 2) * 64 + (ai & 3) * 16 + quad * 4 + r;
        float v = acc[ai][ni][r] + bv;
        if (EPI == 0) {
          if (gn < 2048) {
            o0[(int64_t)gm * 2048 + gn] = (__bf16)(gn < 1024 ? v * 0.125f : v);
          } else {
            const int nn = gn - 2048, hh = nn >> 6, d = nn & 63;
            const int s = gm >> 3, b = gm & 7;  // m = s*8 + b
            o2[((b * 16 + hh) * 64 + d) * 1024 + s] = (__bf16)v;
          }
        } else {  // EPI 2: relu(+bias)
          v = fmaxf(v, 0.f);
          o0[(int64_t)gm * N + gn] = (__bf16)v;
        }
      }
    }
  }
}

// ---------------------------------------------------------------------------
// gemm_db64: R11-verified 128x128 BK=64 double-buffered loop.
// ---------------------------------------------------------------------------
template <int EPI>
__global__ __launch_bounds__(256, 2) void gemm_db64(
    const __bf16* __restrict__ A, const __bf16* __restrict__ Bt,
    const float* __restrict__ bias, const float* __restrict__ resf,
    const __bf16* __restrict__ resb, __bf16* __restrict__ o0,
    __bf16* __restrict__ o2, int M, int N, int K, int ldb) {
  __shared__ __align__(16) __bf16 As[2][2][128 * 32];
  __shared__ __align__(16) __bf16 Bs[2][2][128 * 32];
  const int tid = threadIdx.x;
  const int w = tid >> 6;
  const int lane = tid & 63;
  const int l16 = lane & 15;
  const int quad = lane >> 4;
  const int wm = (w & 1) * 64;
  const int wn = (w >> 1) * 64;
  const int bm = blockIdx.y * 128;
  const int bn = blockIdx.x * 128;

  floatx4 acc[4][4];
#pragma unroll
  for (int i = 0; i < 4; ++i)
#pragma unroll
    for (int j = 0; j < 4; ++j) acc[i][j] = (floatx4){0.f, 0.f, 0.f, 0.f};

  const int arow = lane >> 2, acol = (lane & 3) * 8;
  const __bf16* Ag = A + (int64_t)(bm + w * 32 + arow) * K + acol;
  const __bf16* Bg = Bt + (int64_t)(bn + w * 32 + arow) * ldb + acol;

  auto STAGE = [&](int b, int k0) {
#pragma unroll
    for (int kh = 0; kh < 2; ++kh) {
      __bf16* AsW = As[b][kh] + (w * 32) * 32;
      async_load16(Ag + k0 + kh * 32, AsW);
      async_load16(Ag + k0 + kh * 32 + 16 * K, AsW + 16 * 32);
      __bf16* BsW = Bs[b][kh] + (w * 32) * 32;
      async_load16(Bg + k0 + kh * 32, BsW);
      async_load16(Bg + k0 + kh * 32 + 16 * ldb, BsW + 16 * 32);
    }
  };

  STAGE(0, 0);
  __syncthreads();

  int cur = 0;
  for (int k0 = 0; k0 < K; k0 += 64) {
    if (k0 + 64 < K) STAGE(cur ^ 1, k0 + 64);
#pragma unroll
    for (int kh = 0; kh < 2; ++kh) {
      bf16x8 af[4], bfr[4];
#pragma unroll
      for (int i = 0; i < 4; ++i) {
        af[i] = *(const bf16x8*)(As[cur][kh] + (wm + i * 16 + l16) * 32 + quad * 8);
        bfr[i] = *(const bf16x8*)(Bs[cur][kh] + (wn + i * 16 + l16) * 32 + quad * 8);
      }
#pragma unroll
      for (int mi = 0; mi < 4; ++mi)
#pragma unroll
        for (int ni = 0; ni < 4; ++ni)
          acc[mi][ni] = __builtin_amdgcn_mfma_f32_16x16x32_bf16(
              af[mi], bfr[ni], acc[mi][ni], 0, 0, 0);
    }
    __syncthreads();
    cur ^= 1;
  }

#pragma unroll
  for (int ni = 0; ni < 4; ++ni) {
    const int gn = bn + wn + ni * 16 + l16;
    const float bv = (EPI == 3) ? 0.f : bias[gn];
#pragma unroll
    for (int mi = 0; mi < 4; ++mi) {
#pragma unroll
      for (int r = 0; r < 4; ++r) {
        const int gm = bm + wm + mi * 16 + quad * 4 + r;
        float v = acc[mi][ni][r] + bv;
        if (EPI == 0) {
          if (gn < 2048) {
            o0[(int64_t)gm * 2048 + gn] = (__bf16)(gn < 1024 ? v * 0.125f : v);
          } else {
            const int nn = gn - 2048, hh = nn >> 6, d = nn & 63;
            const int s = gm >> 3, b = gm & 7;
            o2[((b * 16 + hh) * 64 + d) * 1024 + s] = (__bf16)v;
          }
        } else {
          if (EPI == 1) v += resf[(int64_t)gm * N + gn];
          if (EPI == 3 || EPI == 4) v += (float)resb[(int64_t)gm * N + gn];
          if (EPI == 2) v = fmaxf(v, 0.f);
          o0[(int64_t)gm * N + gn] = (__bf16)v;
        }
      }
    }
  }
}

// ---------------------------------------------------------------------------
// gemm_db: R8-verified 128x128 BK=32 loop (fp32-A fallback path).
// ---------------------------------------------------------------------------
constexpr int BM = 128, BN = 128, BK = 32;

template <typename AT, int EPI>
__global__ __launch_bounds__(256, 2) void gemm_db(
    const AT* __restrict__ A, const __bf16* __restrict__ Bt,
    const float* __restrict__ bias, const float* __restrict__ resf,
    const __bf16* __restrict__ resb, __bf16* __restrict__ o0,
    __bf16* __restrict__ o2, int M, int N, int K, int ldb) {
  constexpr bool AF = sizeof(AT) == 4;
  __shared__ __align__(16) __bf16 As[2][BM * BK];
  __shared__ __align__(16) __bf16 Bs[2][BN * BK];
  const int tid = threadIdx.x;
  const int w = tid >> 6;
  const int lane = tid & 63;
  const int l16 = lane & 15;
  const int quad = lane >> 4;
  const int wm = (w & 1) * 64;
  const int wn = (w >> 1) * 64;
  const int bm = blockIdx.y * BM;
  const int bn = blockIdx.x * BN;

  floatx4 acc[4][4];
#pragma unroll
  for (int i = 0; i < 4; ++i)
#pragma unroll
    for (int j = 0; j < 4; ++j) acc[i][j] = (floatx4){0.f, 0.f, 0.f, 0.f};

  const int srow = tid >> 2, scol = (tid & 3) * 8;
  const int arow = lane >> 2, acol = (lane & 3) * 8;
  const AT* Ag;
  if constexpr (AF) Ag = A + (int64_t)(bm + srow) * K + scol;
  else Ag = A + (int64_t)(bm + w * 32 + arow) * K + acol;
  const __bf16* Bg = Bt + (int64_t)(bn + w * 32 + arow) * ldb + acol;

  bf16x8 a0, a1;
  if constexpr (AF) {
    a0 = ld8(Ag);
    a1 = ld8(Ag + (int64_t)64 * K);
    *(bf16x8*)(As[0] + tid * 8) = a0;
    *(bf16x8*)(As[0] + 2048 + tid * 8) = a1;
    if (BK < K) {
      a0 = ld8(Ag + BK);
      a1 = ld8(Ag + BK + (int64_t)64 * K);
    }
  } else {
    __bf16* AsW = As[0] + (w * 32) * BK;
    async_load16(Ag, AsW);
    async_load16(Ag + 16 * K, AsW + 16 * BK);
  }
  {
    __bf16* BsW = Bs[0] + (w * 32) * BK;
    async_load16(Bg, BsW);
    async_load16(Bg + 16 * ldb, BsW + 16 * BK);
  }
  __syncthreads();

  int cur = 0;
  for (int k0 = 0; k0 < K; k0 += BK) {
    const bool more = (k0 + BK) < K;
    if (more) {
      if constexpr (AF) {
        *(bf16x8*)(As[cur ^ 1] + tid * 8) = a0;
        *(bf16x8*)(As[cur ^ 1] + 2048 + tid * 8) = a1;
        if (k0 + 2 * BK < K) {
          a0 = ld8(Ag + k0 + 2 * BK);
          a1 = ld8(Ag + k0 + 2 * BK + (int64_t)64 * K);
        }
      } else {
        __bf16* AsW = As[cur ^ 1] + (w * 32) * BK;
        async_load16(Ag + k0 + BK, AsW);
        async_load16(Ag + k0 + BK + 16 * K, AsW + 16 * BK);
      }
      __bf16* BsW = Bs[cur ^ 1] + (w * 32) * BK;
      async_load16(Bg + k0 + BK, BsW);
      async_load16(Bg + k0 + BK + 16 * ldb, BsW + 16 * BK);
    }
    bf16x8 af[4], bfr[4];
#pragma unroll
    for (int i = 0; i < 4; ++i) {
      af[i] = *(const bf16x8*)(As[cur] + (wm + i * 16 + l16) * BK + quad * 8);
      bfr[i] = *(const bf16x8*)(Bs[cur] + (wn + i * 16 + l16) * BK + quad * 8);
    }
#pragma unroll
    for (int mi = 0; mi < 4; ++mi)
#pragma unroll
      for (int ni = 0; ni < 4; ++ni)
        acc[mi][ni] = __builtin_amdgcn_mfma_f32_16x16x32_bf16(
            af[mi], bfr[ni], acc[mi][ni], 0, 0, 0);
    __syncthreads();
    cur ^= 1;
  }

#pragma unroll
  for (int ni = 0; ni < 4; ++ni) {
    const int gn = bn + wn + ni * 16 + l16;
    const float bv = (EPI == 3) ? 0.f : bias[gn];
#pragma unroll
    for (int mi = 0; mi < 4; ++mi) {
#pragma unroll
      for (int r = 0; r < 4; ++r) {
        const int gm = bm + wm + mi * 16 + quad * 4 + r;
        float v = acc[mi][ni][r] + bv;
        if (EPI == 0) {
          if (gn < 2048) {
            o0[(int64_t)gm * 2048 + gn] = (__bf16)(gn < 1024 ? v * 0.125f : v);
          } else {
            const int nn = gn - 2048, hh = nn >> 6, d = nn & 63;
            const int s = gm >> 3, b = gm & 7;
            o2[((b * 16 + hh) * 64 + d) * 1024 + s] = (__bf16)v;
          }
        } else {
          if (EPI == 1) v += resf[(int64_t)gm * N + gn];
          if (EPI == 3 || EPI == 4) v += (float)resb[(int64_t)gm * N + gn];
          if (EPI == 2) v = fmaxf(v, 0.f);
          o0[(int64_t)gm * N + gn] = (__bf16)v;
        }
      }
    }
  }
}

// ---------------------------------------------------------------------------
// Flash attention, no-max softmax. (R8-verified, unchanged.)
// ---------------------------------------------------------------------------
__global__ __launch_bounds__(256) void attn_flash(
    const __bf16* __restrict__ qk, const __bf16* __restrict__ vT,
    __bf16* __restrict__ ctx) {
  constexpr int S = 1024, PSTR = 36;
  constexpr int ROWSTR = 8 * 2048;
  __shared__ __align__(16) __bf16 Kb[2][2048];
  __shared__ __align__(16) __bf16 Vb[2][2048];
  __shared__ __align__(16) __bf16 Pt[4][32 * PSTR];
  const int tid = threadIdx.x;
  const int w = tid >> 6;
  const int lane = tid & 63;
  const int l16 = lane & 15;
  const int quad = lane >> 4;
  const int bh = blockIdx.y, bidx = bh >> 4, h = bh & 15;
  const int qbase = blockIdx.x * 128 + w * 32;

  const __bf16* qp =
      qk + ((int64_t)(qbase + l16) * 8 + bidx) * 2048 + h * 64 + quad * 8;
  bf16x8 aq[2][2];
  aq[0][0] = *(const bf16x8*)qp;
  aq[0][1] = *(const bf16x8*)(qp + 32);
  aq[1][0] = *(const bf16x8*)(qp + 16 * ROWSTR);
  aq[1][1] = *(const bf16x8*)(qp + 16 * ROWSTR + 32);

  const __bf16* kg = qk + 1024 +
      ((int64_t)((w >> 1) * 16 + l16) * 8 + bidx) * 2048 + h * 64 +
      ((w & 1) * 4 + quad) * 8;
  const __bf16* vg =
      vT + ((int64_t)bh * 64 + w * 16 + l16) * 1024 + quad * 8;
  __bf16* pt = Pt[w];

  floatx4 o[2][4];
  float la[2][4];
#pragma unroll
  for (int rt = 0; rt < 2; ++rt)
#pragma unroll
    for (int j = 0; j < 4; ++j) {
      o[rt][j] = (floatx4){0.f, 0.f, 0.f, 0.f};
      la[rt][j] = 0.f;
    }

  async_load16(kg, Kb[0] + w * 512);
  async_load16(vg, Vb[0] + w * 512);
  int cur = 0;

  for (int t0 = 0; t0 < S; t0 += 32) {
    __syncthreads();
    if (t0 + 32 < S) {
      async_load16(kg + (int64_t)(t0 + 32) * ROWSTR, Kb[cur ^ 1] + w * 512);
      async_load16(vg + (t0 + 32), Vb[cur ^ 1] + w * 512);
    }

    bf16x8 kf[4], vv[4];
#pragma unroll
    for (int f = 0; f < 4; ++f) {
      kf[f] = *(const bf16x8*)(Kb[cur] + f * 512 + lane * 8);
      vv[f] = *(const bf16x8*)(Vb[cur] + f * 512 + lane * 8);
    }

    floatx4 s00 = (floatx4){0.f, 0.f, 0.f, 0.f};
    floatx4 s01 = (floatx4){0.f, 0.f, 0.f, 0.f};
    floatx4 s10 = (floatx4){0.f, 0.f, 0.f, 0.f};
    floatx4 s11 = (floatx4){0.f, 0.f, 0.f, 0.f};
    s00 = __builtin_amdgcn_mfma_f32_16x16x32_bf16(aq[0][0], kf[0], s00, 0, 0, 0);
    s00 = __builtin_amdgcn_mfma_f32_16x16x32_bf16(aq[0][1], kf[1], s00, 0, 0, 0);
    s01 = __builtin_amdgcn_mfma_f32_16x16x32_bf16(aq[0][0], kf[2], s01, 0, 0, 0);
    s01 = __builtin_amdgcn_mfma_f32_16x16x32_bf16(aq[0][1], kf[3], s01, 0, 0, 0);
    s10 = __builtin_amdgcn_mfma_f32_16x16x32_bf16(aq[1][0], kf[0], s10, 0, 0, 0);
    s10 = __builtin_amdgcn_mfma_f32_16x16x32_bf16(aq[1][1], kf[1], s10, 0, 0, 0);
    s11 = __builtin_amdgcn_mfma_f32_16x16x32_bf16(aq[1][0], kf[2], s11, 0, 0, 0);
    s11 = __builtin_amdgcn_mfma_f32_16x16x32_bf16(aq[1][1], kf[3], s11, 0, 0, 0);

#pragma unroll
    for (int r = 0; r < 4; ++r) {
      const int row0 = (quad * 4 + r) * PSTR;
      const float p00 = __expf(s00[r]);
      const float p01 = __expf(s01[r]);
      la[0][r] += p00 + p01;
      pt[row0 + l16] = (__bf16)p00;
      pt[row0 + 16 + l16] = (__bf16)p01;
      const int row1 = (16 + quad * 4 + r) * PSTR;
      const float p10 = __expf(s10[r]);
      const float p11 = __expf(s11[r]);
      la[1][r] += p10 + p11;
      pt[row1 + l16] = (__bf16)p10;
      pt[row1 + 16 + l16] = (__bf16)p11;
    }
    const bf16x8 pa0 = *(const bf16x8*)(pt + l16 * PSTR + quad * 8);
    const bf16x8 pa1 = *(const bf16x8*)(pt + (16 + l16) * PSTR + quad * 8);
#pragma unroll
    for (int j = 0; j < 4; ++j) {
      o[0][j] = __builtin_amdgcn_mfma_f32_16x16x32_bf16(pa0, vv[j], o[0][j], 0, 0, 0);
      o[1][j] = __builtin_amdgcn_mfma_f32_16x16x32_bf16(pa1, vv[j], o[1][j], 0, 0, 0);
    }
    cur ^= 1;
  }

#pragma unroll
  for (int rt = 0; rt < 2; ++rt)
#pragma unroll
    for (int r = 0; r < 4; ++r) {
      float s = la[rt][r];
      s += __shfl_xor(s, 1, 64);
      s += __shfl_xor(s, 2, 64);
      s += __shfl_xor(s, 4, 64);
      s += __shfl_xor(s, 8, 64);
      la[rt][r] = s;
    }
#pragma unroll
  for (int rt = 0; rt < 2; ++rt)
#pragma unroll
    for (int j = 0; j < 4; ++j)
#pragma unroll
      for (int r = 0; r < 4; ++r) {
        const int row = qbase + rt * 16 + quad * 4 + r;
        const int gm = row * 8 + bidx;
        ctx[(int64_t)gm * 1024 + h * 64 + j * 16 + l16] =
            (__bf16)(o[rt][j][r] / la[rt][r]);
      }
}

// ---------------------------------------------------------------------------
// LayerNorm over last dim (1024). One block (256 thr) per row. Vectorized.
// ---------------------------------------------------------------------------
template <typename OutT>
__global__ __launch_bounds__(256) void ln_kernel(const __bf16* __restrict__ y,
                                                 const float* __restrict__ g,
                                                 const float* __restrict__ be,
                                                 OutT* __restrict__ out) {
  constexpr int D = 1024;
  const int row = blockIdx.x;
  const int tid = threadIdx.x;
  const __bf16* yr = y + (int64_t)row * D;
  const int c0 = tid * 4;
  const bf16x4 raw = *(const bf16x4*)(yr + c0);
  float v[4];
#pragma unroll
  for (int j = 0; j < 4; ++j) v[j] = (float)raw[j];
  float s = v[0] + v[1] + v[2] + v[3];
  float sq = v[0] * v[0] + v[1] * v[1] + v[2] * v[2] + v[3] * v[3];
#pragma unroll
  for (int off = 1; off < 64; off <<= 1) {
    s += __shfl_xor(s, off, 64);
    sq += __shfl_xor(sq, off, 64);
  }
  __shared__ float ls[4], lq[4];
  const int w = tid >> 6;
  if ((tid & 63) == 0) {
    ls[w] = s;
    lq[w] = sq;
  }
  __syncthreads();
  s = ls[0] + ls[1] + ls[2] + ls[3];
  sq = lq[0] + lq[1] + lq[2] + lq[3];
  const float mean = s * (1.f / D);
  const float var = sq * (1.f / D) - mean * mean;
  const float inv = rsqrtf(var + 1e-5f);
  const floatx4 gv = *(const floatx4*)(g + c0);
  const floatx4 bv = *(const floatx4*)(be + c0);
  if constexpr (sizeof(OutT) == 4) {
    floatx4 ov;
#pragma unroll
    for (int j = 0; j < 4; ++j) ov[j] = (v[j] - mean) * inv * gv[j] + bv[j];
    *(floatx4*)((float*)out + (int64_t)row * D + c0) = ov;
  } else {
    bf16x4 ov;
#pragma unroll
    for (int j = 0; j < 4; ++j)
      ov[j] = (__bf16)((v[j] - mean) * inv * gv[j] + bv[j]);
    *(bf16x4*)((__bf16*)out + (int64_t)row * D + c0) = ov;
  }
}

// ---------------------------------------------------------------------------
// Memory map, big path (ws >= 48 MiB; d_out 32 MiB doubles as scratch):
//   QKV       qk ws[0,32)  srcb ws[32,48)   vT out[0,16)  ipwb out[16,22)
//   attn      qk (r)                        ctx -> out[16,32)
//   out-proj  owb ws[0,2)  y ws[2,18)       ctx (r), src (r)
//   LN1       y (r)                         x -> out[0,16)
//   FFN       z ws[0,16)  h ws[16,48)       x (r), w1b out[16,24), w2b out[24,32)
//   LN2       z (r)                         d_out fp32 [0,32)
// gemm8p (256x256): QKV (12,32)=384 blk, G1 (8,32)=256 blk.
// gemm_db64 (128x128): out-proj (8,64)=512, G2 (8,64)=512.
// ---------------------------------------------------------------------------
extern "C" void kernel_launch(void* const* d_in, const int* in_sizes, int n_in,
                              void* d_out, int out_size, void* d_ws,
                              size_t ws_size, hipStream_t stream) {
  const float* src = (const float*)d_in[0];        // [8192,1024]
  const float* in_proj_w = (const float*)d_in[1];  // [3072,1024]
  const float* in_proj_b = (const float*)d_in[2];
  const float* out_w = (const float*)d_in[3];      // [1024,1024]
  const float* out_b = (const float*)d_in[4];
  const float* w1 = (const float*)d_in[5];         // [4096,1024]
  const float* b1 = (const float*)d_in[6];
  const float* w2 = (const float*)d_in[7];         // [1024,4096]
  const float* b2 = (const float*)d_in[8];
  const float* g1 = (const float*)d_in[9];
  const float* be1 = (const float*)d_in[10];
  const float* g2 = (const float*)d_in[11];
  const float* be2 = (const float*)d_in[12];

  char* ws = (char*)d_ws;
  char* out8 = (char*)d_out;
  __bf16* qkb = (__bf16*)ws;                       // ws[0,32M)
  __bf16* vb = (__bf16*)out8;                      // out[0,16M)
  __bf16* ipwb = (__bf16*)(out8 + (16ull << 20));  // out[16,22M)
  __bf16* srcb = (__bf16*)(ws + (32ull << 20));    // ws[32,48M)
  __bf16* ctxb = (__bf16*)(out8 + (16ull << 20));  // out[16,32M)
  __bf16* owb = (__bf16*)ws;                       // ws[0,2M)
  __bf16* yb = (__bf16*)(ws + (2ull << 20));       // ws[2,18M)
  __bf16* xb = (__bf16*)out8;                      // out[0,16M)

  const bool big = ws_size >= ((size_t)48 << 20);

  if (big) {
    __bf16* w1b = (__bf16*)(out8 + (16ull << 20));   // out[16,24M)
    __bf16* w2b = (__bf16*)(out8 + (24ull << 20));   // out[24,32M)
    __bf16* hb = (__bf16*)(ws + (16ull << 20));      // ws[16,48M) [8192,2048]
    __bf16* zb = (__bf16*)ws;                        // ws[0,16M)

    hipFuncSetAttribute(reinterpret_cast<const void*>(&gemm8p<0>),
                        hipFuncAttributeMaxDynamicSharedMemorySize, 131072);
    hipFuncSetAttribute(reinterpret_cast<const void*>(&gemm8p<2>),
                        hipFuncAttributeMaxDynamicSharedMemorySize, 131072);

    // 0/1. weight + src converts, QKV projection (8-phase 256^2)
    cvt_kernel<<<1536, 256, 0, stream>>>(in_proj_w, ipwb, 3 * 1024 * 1024);
    cvt_kernel<<<4096, 256, 0, stream>>>(src, srcb, 8 * 1024 * 1024);
    gemm8p<0><<<dim3(12, 32), 512, 131072, stream>>>(
        srcb, ipwb, in_proj_b, nullptr, nullptr, qkb, vb, 8192, 3072, 1024,
        1024);
    // 2. flash attention (ctx overwrites dead ipwb region)
    attn_flash<<<dim3(8, 128), 256, 0, stream>>>(qkb, vb, ctxb);
    // 3. out-proj + residual(src fp32)
    cvt_kernel<<<512, 256, 0, stream>>>(out_w, owb, 1024 * 1024);
    gemm_db64<1><<<dim3(8, 64), 256, 0, stream>>>(
        ctxb, owb, out_b, src, nullptr, yb, nullptr, 8192, 1024, 1024, 1024);
    // 4. LN1 -> x (overwrites dead vT)
    ln_kernel<__bf16><<<8192, 256, 0, stream>>>(yb, g1, be1, xb);
    // 5. FFN weights -> bf16 (ctx region dead after out-proj)
    cvt_kernel<<<2048, 256, 0, stream>>>(w1, w1b, 4 * 1024 * 1024);
    cvt_kernel<<<2048, 256, 0, stream>>>(w2, w2b, 4 * 1024 * 1024);
    // 6. FFN in 2 N=2048 halves: G1 8-phase, G2 db64
    for (int q = 0; q < 2; ++q) {
      gemm8p<2><<<dim3(8, 32), 512, 131072, stream>>>(
          xb, w1b + (int64_t)q * 2048 * 1024, b1 + q * 2048, nullptr, nullptr,
          hb, nullptr, 8192, 2048, 1024, 1024);
      if (q == 0)
        gemm_db64<4><<<dim3(8, 64), 256, 0, stream>>>(
            hb, w2b + q * 2048, b2, nullptr, xb, zb, nullptr, 8192, 1024, 2048,
            4096);
      else
        gemm_db64<3><<<dim3(8, 64), 256, 0, stream>>>(
            hb, w2b + q * 2048, nullptr, nullptr, zb, zb, nullptr, 8192, 1024,
            2048, 4096);
    }
    // 7. LN2 -> output (fp32)
    ln_kernel<float><<<8192, 256, 0, stream>>>(zb, g2, be2, (float*)d_out);
  } else {
    // fallback (ws 32M): fp32-A QKV, FFN in 4 N=1024 quarters (R8-verified)
    __bf16* w1b = (__bf16*)ws;                       // ws[0,8M)
    __bf16* w2b = (__bf16*)(ws + (8ull << 20));      // ws[8,16M)
    __bf16* hb = (__bf16*)(out8 + (16ull << 20));    // out[16,32M)
    __bf16* zb = (__bf16*)(ws + (16ull << 20));      // ws[16,32M)

    cvt_kernel<<<1536, 256, 0, stream>>>(in_proj_w, ipwb, 3 * 1024 * 1024);
    gemm_db<float, 0><<<dim3(24, 64), 256, 0, stream>>>(
        src, ipwb, in_proj_b, nullptr, nullptr, qkb, vb, 8192, 3072, 1024,
        1024);
    attn_flash<<<dim3(8, 128), 256, 0, stream>>>(qkb, vb, ctxb);
    cvt_kernel<<<512, 256, 0, stream>>>(out_w, owb, 1024 * 1024);
    gemm_db<__bf16, 1><<<dim3(8, 64), 256, 0, stream>>>(
        ctxb, owb, out_b, src, nullptr, yb, nullptr, 8192, 1024, 1024, 1024);
    ln_kernel<__bf16><<<8192, 256, 0, stream>>>(yb, g1, be1, xb);
    cvt_kernel<<<2048, 256, 0, stream>>>(w1, w1b, 4 * 1024 * 1024);
    cvt_kernel<<<2048, 256, 0, stream>>>(w2, w2b, 4 * 1024 * 1024);
    for (int qd = 0; qd < 4; ++qd) {
      gemm_db<__bf16, 2><<<dim3(8, 64), 256, 0, stream>>>(
          xb, w1b + (int64_t)qd * 1024 * 1024, b1 + qd * 1024, nullptr,
          nullptr, hb, nullptr, 8192, 1024, 1024, 1024);
      if (qd == 0)
        gemm_db<__bf16, 4><<<dim3(8, 64), 256, 0, stream>>>(
            hb, w2b + qd * 1024, b2, nullptr, xb, zb, nullptr, 8192, 1024,
            1024, 4096);
      else
        gemm_db<__bf16, 3><<<dim3(8, 64), 256, 0, stream>>>(
            hb, w2b + qd * 1024, nullptr, nullptr, zb, zb, nullptr, 8192, 1024,
            1024, 4096);
    }
    ln_kernel<float><<<8192, 256, 0, stream>>>(zb, g2, be2, (float*)d_out);
  }
}